// Round 9
// baseline (591.711 us; speedup 1.0000x reference)
//
#include <hip/hip_runtime.h>
#include <hip/hip_bf16.h>

// GraphMatchingLayer, round 9:
//  - k_edge6: round-7 edge kernel with the "memory"-clobber fence replaced by
//    __builtin_amdgcn_s_waitcnt(0xC07F) (+sched_barrier) -> w[32]/u stay in
//    VGPRs (r8 showed VGPR=36: everything was re-loaded per chunk).
//    PLUS fused node MLP epilogue through the same wave-private LDS strip
//    (uniform b128 broadcasts, per-lane column weight loads) -> k_node3 and
//    the 51 MB H round-trip are gone.
//  - k_apply2: bsum prefix computed per-block by wave 0 -> k_scanb gone.
//  - 7 dispatches total.

#define TPB 256

// lgkmcnt(0)-only wait, no IR memory clobber; sched_barriers pin ordering.
#define LDS_FENCE() do {                          \
    __builtin_amdgcn_sched_barrier(0);            \
    __builtin_amdgcn_s_waitcnt(0xC07F);           \
    __builtin_amdgcn_sched_barrier(0);            \
  } while (0)

// 32-wide dense segment (weights via wave-uniform address -> scalar loads)
#define SEG32(SRC, NCH, KB, W, COL, ACC)                                \
  for (int kc_ = 0; kc_ < (NCH); ++kc_) {                               \
    const float4 a_ = ((const float4*)(SRC))[kc_];                      \
    const float av_[4] = {a_.x, a_.y, a_.z, a_.w};                      \
    _Pragma("unroll")                                                   \
    for (int j_ = 0; j_ < 4; ++j_) {                                    \
      const float ak_ = av_[j_];                                        \
      const float* wr_ = (W) + ((KB) + kc_ * 4 + j_) * 64 + (COL);      \
      _Pragma("unroll")                                                 \
      for (int cc_ = 0; cc_ < 32; ++cc_)                                \
        ACC[cc_] = fmaf(ak_, wr_[cc_], ACC[cc_]);                       \
    }                                                                   \
  }

// ---------------- CSR build ----------------

__global__ __launch_bounds__(TPB)
void k_hist(const int* __restrict__ ei, int* __restrict__ deg, int E) {
  int e = blockIdx.x * TPB + threadIdx.x;
  if (e < E) atomicAdd(&deg[ei[e]], 1);
}

__global__ __launch_bounds__(TPB)
void k_red(const int* __restrict__ deg, int* __restrict__ bsum, int N) {
  __shared__ int s[TPB];
  const int tid = threadIdx.x;
  const int g = (blockIdx.x * TPB + tid) * 4;
  int v = 0;
  #pragma unroll
  for (int j = 0; j < 4; ++j) if (g + j < N) v += deg[g + j];
  s[tid] = v;
  __syncthreads();
  for (int off = TPB / 2; off > 0; off >>= 1) {
    if (tid < off) s[tid] += s[tid + off];
    __syncthreads();
  }
  if (tid == 0) bsum[blockIdx.x] = s[0];
}

// block-local scan + per-block recomputed bsum prefix (k_scanb folded in)
__global__ __launch_bounds__(TPB)
void k_apply2(const int* __restrict__ deg, const int* __restrict__ bsum,
              int* __restrict__ cur, int N) {
  __shared__ int s[TPB];
  __shared__ int sbase;
  const int tid = threadIdx.x;
  const int g = (blockIdx.x * TPB + tid) * 4;

  if (tid < 64) {                       // wave 0: sum bsum[0..blockIdx)
    int v = 0;
    for (int i = tid; i < (int)blockIdx.x; i += 64) v += bsum[i];
    #pragma unroll
    for (int off = 32; off > 0; off >>= 1) v += __shfl_down(v, off);
    if (tid == 0) sbase = v;
  }

  int d[4];
  int v = 0;
  #pragma unroll
  for (int j = 0; j < 4; ++j) { d[j] = (g + j < N) ? deg[g + j] : 0; v += d[j]; }
  s[tid] = v;
  __syncthreads();
  for (int off = 1; off < TPB; off <<= 1) {
    int t = (tid >= off) ? s[tid - off] : 0;
    __syncthreads();
    s[tid] += t;
    __syncthreads();
  }
  int base = sbase + s[tid] - v;
  #pragma unroll
  for (int j = 0; j < 4; ++j)
    if (g + j < N) { cur[g + j] = base; base += d[j]; }
}

__global__ __launch_bounds__(TPB)
void k_scatter(const int* __restrict__ ei, int* __restrict__ cur,
               int2* __restrict__ ec, int E) {
  int e = blockIdx.x * TPB + threadIdx.x;
  if (e < E) {
    const int r = ei[e];
    const int c = ei[E + e];
    int p = atomicAdd(&cur[r], 1);
    ec[p] = make_int2(e, c);
  }
}

// ---------------- U/V precompute: 4-way wave split ----------------

__global__ __launch_bounds__(TPB)
void k_prep3(const float* __restrict__ x,
             const float* __restrict__ ew1, const float* __restrict__ eb1,
             float* __restrict__ U, float* __restrict__ V, int N)
{
  const int t = blockIdx.x * TPB + threadIdx.x;
  const int wv = __builtin_amdgcn_readfirstlane(t >> 6);
  const int lane = t & 63;
  const int q = wv & 3;
  const int n = (wv >> 2) * 64 + lane;
  if (n >= N) return;

  const int uv = q >> 1;
  const int h = (q & 1) * 32;
  const float* W = ew1 + uv * 64 * 64;

  float acc[32];
  if (uv) {
    #pragma unroll
    for (int j = 0; j < 32; ++j) acc[j] = 0.f;
  } else {
    #pragma unroll
    for (int j = 0; j < 32; ++j) acc[j] = eb1[h + j];
  }
  SEG32(x + (size_t)n * 64, 16, 0, W, h, acc)

  float* dst = (uv ? V : U) + (size_t)n * 64 + h;
  float4* d4 = (float4*)dst;
  #pragma unroll
  for (int c4 = 0; c4 < 8; ++c4)
    d4[c4] = make_float4(acc[c4*4+0], acc[c4*4+1], acc[c4*4+2], acc[c4*4+3]);
}

// ---------------- fused edge + node kernel ----------------

__global__ __launch_bounds__(TPB)
void k_edge6(const float* __restrict__ U, const float* __restrict__ V,
             const float* __restrict__ ea, const float* __restrict__ x,
             const float* __restrict__ ew1,
             const float* __restrict__ ew2, const float* __restrict__ eb2,
             const float* __restrict__ nw1, const float* __restrict__ nb1,
             const float* __restrict__ nw2, const float* __restrict__ nb2,
             const int* __restrict__ deg, const int* __restrict__ cur,
             const int2* __restrict__ ec,
             float* __restrict__ out, int N)
{
  __shared__ float sbuf[4 * 256];        // 1 KB wave-private strip each

  const int lane = threadIdx.x & 63;
  const int wid  = __builtin_amdgcn_readfirstlane(threadIdx.x >> 6);
  const int n    = __builtin_amdgcn_readfirstlane((int)blockIdx.x * 4 + wid);
  if (n >= N) return;

  const int d  = __builtin_amdgcn_readfirstlane(deg[n]);
  const int s0 = __builtin_amdgcn_readfirstlane(cur[n]) - d;

  float* lw = sbuf + wid * 256;
  const int g = lane >> 3;
  const int o = lane & 7;

  // this lane's W1c column (register-resident now that the clobber is gone)
  float w[32];
  #pragma unroll
  for (int k = 0; k < 32; ++k) w[k] = ew1[(128 + k) * 64 + lane];

  const float u = U[(size_t)n * 64 + lane];
  const int2* ecp = ec + s0;
  float acc = 0.f;

  for (int i = 0; i < d; i += 8) {
    const int rem = d - i;
    const int gg = (g < rem) ? g : rem - 1;

    const int2 ecv = ecp[i + gg];
    const float4 eav = *(const float4*)(ea + (size_t)ecv.x * 32 + o * 4);

    const int c0 = __builtin_amdgcn_readlane(ecv.y, 0);
    const int c1 = __builtin_amdgcn_readlane(ecv.y, 8);
    const int c2 = __builtin_amdgcn_readlane(ecv.y, 16);
    const int c3 = __builtin_amdgcn_readlane(ecv.y, 24);
    const int c4 = __builtin_amdgcn_readlane(ecv.y, 32);
    const int c5 = __builtin_amdgcn_readlane(ecv.y, 40);
    const int c6 = __builtin_amdgcn_readlane(ecv.y, 48);
    const int c7 = __builtin_amdgcn_readlane(ecv.y, 56);
    const float v0 = V[(size_t)c0 * 64 + lane];
    const float v1 = V[(size_t)c1 * 64 + lane];
    const float v2 = V[(size_t)c2 * 64 + lane];
    const float v3 = V[(size_t)c3 * 64 + lane];
    const float v4 = V[(size_t)c4 * 64 + lane];
    const float v5 = V[(size_t)c5 * 64 + lane];
    const float v6 = V[(size_t)c6 * 64 + lane];
    const float v7 = V[(size_t)c7 * 64 + lane];

    *(float4*)(lw + lane * 4) = eav;     // wave-private; LDS is in-order per wave
    LDS_FENCE();

    const float vs[8] = {v0, v1, v2, v3, v4, v5, v6, v7};
    #pragma unroll
    for (int j = 0; j < 8; ++j) {
      const float* er = lw + j * 32;     // uniform addr -> broadcast reads
      float t0 = u, t1 = 0.f, t2 = 0.f, t3 = 0.f;
      #pragma unroll
      for (int k = 0; k < 32; k += 4) {
        t0 = fmaf(er[k + 0], w[k + 0], t0);
        t1 = fmaf(er[k + 1], w[k + 1], t1);
        t2 = fmaf(er[k + 2], w[k + 2], t2);
        t3 = fmaf(er[k + 3], w[k + 3], t3);
      }
      const float s = fmaxf(((t0 + t1) + (t2 + t3)) + vs[j], 0.f);
      acc += (j < rem) ? s : 0.f;
    }
    LDS_FENCE();                         // strip reads done before next overwrite
  }

  // ---------- fused node MLP (same wave, strip reuse, no block barriers) ----------
  const float xv = x[(size_t)n * 64 + lane];
  lw[lane]      = acc;                   // H[n][*]
  lw[64 + lane] = xv;                    // x[n][*]
  LDS_FENCE();

  // stage A: agg = deg*eb2 + H @ ew2
  float aggv = (float)d * eb2[lane];
  #pragma unroll
  for (int kc = 0; kc < 16; ++kc) {
    const float4 hk = *(const float4*)(lw + kc * 4);
    aggv = fmaf(hk.x, ew2[(kc * 4 + 0) * 64 + lane], aggv);
    aggv = fmaf(hk.y, ew2[(kc * 4 + 1) * 64 + lane], aggv);
    aggv = fmaf(hk.z, ew2[(kc * 4 + 2) * 64 + lane], aggv);
    aggv = fmaf(hk.w, ew2[(kc * 4 + 3) * 64 + lane], aggv);
  }
  lw[128 + lane] = aggv;
  LDS_FENCE();

  // stage B: nacc = nb1 + x @ nw1[0:64] + agg @ nw1[64:128]
  float nv = nb1[lane];
  #pragma unroll
  for (int kc = 0; kc < 16; ++kc) {
    const float4 xk = *(const float4*)(lw + 64 + kc * 4);
    nv = fmaf(xk.x, nw1[(kc * 4 + 0) * 64 + lane], nv);
    nv = fmaf(xk.y, nw1[(kc * 4 + 1) * 64 + lane], nv);
    nv = fmaf(xk.z, nw1[(kc * 4 + 2) * 64 + lane], nv);
    nv = fmaf(xk.w, nw1[(kc * 4 + 3) * 64 + lane], nv);
  }
  #pragma unroll
  for (int kc = 0; kc < 16; ++kc) {
    const float4 ak = *(const float4*)(lw + 128 + kc * 4);
    nv = fmaf(ak.x, nw1[(64 + kc * 4 + 0) * 64 + lane], nv);
    nv = fmaf(ak.y, nw1[(64 + kc * 4 + 1) * 64 + lane], nv);
    nv = fmaf(ak.z, nw1[(64 + kc * 4 + 2) * 64 + lane], nv);
    nv = fmaf(ak.w, nw1[(64 + kc * 4 + 3) * 64 + lane], nv);
  }
  lw[192 + lane] = fmaxf(nv, 0.f);
  LDS_FENCE();

  // stage C: out = nb2 + relu(nacc) @ nw2
  float ov = nb2[lane];
  #pragma unroll
  for (int kc = 0; kc < 16; ++kc) {
    const float4 rk = *(const float4*)(lw + 192 + kc * 4);
    ov = fmaf(rk.x, nw2[(kc * 4 + 0) * 64 + lane], ov);
    ov = fmaf(rk.y, nw2[(kc * 4 + 1) * 64 + lane], ov);
    ov = fmaf(rk.z, nw2[(kc * 4 + 2) * 64 + lane], ov);
    ov = fmaf(rk.w, nw2[(kc * 4 + 3) * 64 + lane], ov);
  }
  out[(size_t)n * 64 + lane] = ov;
}

// ---------------- launch ----------------

extern "C" void kernel_launch(void* const* d_in, const int* in_sizes, int n_in,
                              void* d_out, int out_size, void* d_ws, size_t ws_size,
                              hipStream_t stream) {
  const float* x   = (const float*)d_in[0];
  const int*   ei  = (const int*)d_in[1];
  const float* ea  = (const float*)d_in[2];
  const float* ew1 = (const float*)d_in[3];
  const float* eb1 = (const float*)d_in[4];
  const float* ew2 = (const float*)d_in[5];
  const float* eb2 = (const float*)d_in[6];
  const float* nw1 = (const float*)d_in[7];
  const float* nb1 = (const float*)d_in[8];
  const float* nw2 = (const float*)d_in[9];
  const float* nb2 = (const float*)d_in[10];
  float* out = (float*)d_out;

  const int N = in_sizes[0] / 64;   // 100000
  const int E = in_sizes[1] / 2;    // 1600000

  // workspace layout
  float* U   = (float*)d_ws;                      // N*64 f32
  float* V   = U + (size_t)N * 64;                // N*64 f32
  int* ib    = (int*)(V + (size_t)N * 64);
  int* deg   = ib;                                // N
  int* cur   = ib + N;                            // N
  int* bsum  = ib + 2 * N;                        // <=512
  int2* ec   = (int2*)(ib + 2 * N + 1024);        // E int2
  const int NT = (N + 3) / 4;
  const int NB = (NT + TPB - 1) / TPB;            // 98

  hipMemsetAsync(deg, 0, (size_t)N * sizeof(int), stream);

  k_hist<<<(E + TPB - 1) / TPB, TPB, 0, stream>>>(ei, deg, E);
  k_red<<<NB, TPB, 0, stream>>>(deg, bsum, N);
  k_apply2<<<NB, TPB, 0, stream>>>(deg, bsum, cur, N);
  k_scatter<<<(E + TPB - 1) / TPB, TPB, 0, stream>>>(ei, cur, ec, E);

  {
    const int nwaves = 4 * ((N + 63) / 64);
    const int nblocks = (nwaves + 3) / 4;
    k_prep3<<<nblocks, TPB, 0, stream>>>(x, ew1, eb1, U, V, N);
  }

  k_edge6<<<(N + 3) / 4, TPB, 0, stream>>>(
      U, V, ea, x, ew1, ew2, eb2, nw1, nb1, nw2, nb2,
      deg, cur, ec, out, N);
}

// Round 10
// 484.331 us; speedup vs baseline: 1.2217x; 1.2217x over previous
//
#include <hip/hip_runtime.h>
#include <hip/hip_bf16.h>

// GraphMatchingLayer, round 10: revert to round-8 structure (separate
// edge/node/prep kernels; fused scanb via k_apply2 kept from r9).
// ONE change in the edge kernel (k_edge7):
//   - fence = builtin s_waitcnt(lgkmcnt0) + sched_barrier (no IR mem clobber)
//   - __launch_bounds__(256, 4) -> 128-VGPR budget so w[32]/u/vs stay
//     register-resident instead of being rematerialized every chunk
//     (r8: VGPR=36, r9: VGPR=44 -> column weights re-loaded per chunk).

#define TPB 256

#define LDS_FENCE() do {                          \
    __builtin_amdgcn_sched_barrier(0);            \
    __builtin_amdgcn_s_waitcnt(0xC07F);           \
    __builtin_amdgcn_sched_barrier(0);            \
  } while (0)

// 32-wide dense segment (weights via wave-uniform address -> scalar loads)
#define SEG32(SRC, NCH, KB, W, COL, ACC)                                \
  for (int kc_ = 0; kc_ < (NCH); ++kc_) {                               \
    const float4 a_ = ((const float4*)(SRC))[kc_];                      \
    const float av_[4] = {a_.x, a_.y, a_.z, a_.w};                      \
    _Pragma("unroll")                                                   \
    for (int j_ = 0; j_ < 4; ++j_) {                                    \
      const float ak_ = av_[j_];                                        \
      const float* wr_ = (W) + ((KB) + kc_ * 4 + j_) * 64 + (COL);      \
      _Pragma("unroll")                                                 \
      for (int cc_ = 0; cc_ < 32; ++cc_)                                \
        ACC[cc_] = fmaf(ak_, wr_[cc_], ACC[cc_]);                       \
    }                                                                   \
  }

// ---------------- CSR build ----------------

__global__ __launch_bounds__(TPB)
void k_hist(const int* __restrict__ ei, int* __restrict__ deg, int E) {
  int e = blockIdx.x * TPB + threadIdx.x;
  if (e < E) atomicAdd(&deg[ei[e]], 1);
}

__global__ __launch_bounds__(TPB)
void k_red(const int* __restrict__ deg, int* __restrict__ bsum, int N) {
  __shared__ int s[TPB];
  const int tid = threadIdx.x;
  const int g = (blockIdx.x * TPB + tid) * 4;
  int v = 0;
  #pragma unroll
  for (int j = 0; j < 4; ++j) if (g + j < N) v += deg[g + j];
  s[tid] = v;
  __syncthreads();
  for (int off = TPB / 2; off > 0; off >>= 1) {
    if (tid < off) s[tid] += s[tid + off];
    __syncthreads();
  }
  if (tid == 0) bsum[blockIdx.x] = s[0];
}

// block-local scan + per-block recomputed bsum prefix (scanb folded in)
__global__ __launch_bounds__(TPB)
void k_apply2(const int* __restrict__ deg, const int* __restrict__ bsum,
              int* __restrict__ cur, int N) {
  __shared__ int s[TPB];
  __shared__ int sbase;
  const int tid = threadIdx.x;
  const int g = (blockIdx.x * TPB + tid) * 4;

  if (tid < 64) {                       // wave 0: sum bsum[0..blockIdx)
    int v = 0;
    for (int i = tid; i < (int)blockIdx.x; i += 64) v += bsum[i];
    #pragma unroll
    for (int off = 32; off > 0; off >>= 1) v += __shfl_down(v, off);
    if (tid == 0) sbase = v;
  }

  int d[4];
  int v = 0;
  #pragma unroll
  for (int j = 0; j < 4; ++j) { d[j] = (g + j < N) ? deg[g + j] : 0; v += d[j]; }
  s[tid] = v;
  __syncthreads();
  for (int off = 1; off < TPB; off <<= 1) {
    int t = (tid >= off) ? s[tid - off] : 0;
    __syncthreads();
    s[tid] += t;
    __syncthreads();
  }
  int base = sbase + s[tid] - v;
  #pragma unroll
  for (int j = 0; j < 4; ++j)
    if (g + j < N) { cur[g + j] = base; base += d[j]; }
}

__global__ __launch_bounds__(TPB)
void k_scatter(const int* __restrict__ ei, int* __restrict__ cur,
               int2* __restrict__ ec, int E) {
  int e = blockIdx.x * TPB + threadIdx.x;
  if (e < E) {
    const int r = ei[e];
    const int c = ei[E + e];
    int p = atomicAdd(&cur[r], 1);
    ec[p] = make_int2(e, c);
  }
}

// ---------------- U/V precompute: 4-way wave split ----------------

__global__ __launch_bounds__(TPB)
void k_prep3(const float* __restrict__ x,
             const float* __restrict__ ew1, const float* __restrict__ eb1,
             float* __restrict__ U, float* __restrict__ V, int N)
{
  const int t = blockIdx.x * TPB + threadIdx.x;
  const int wv = __builtin_amdgcn_readfirstlane(t >> 6);
  const int lane = t & 63;
  const int q = wv & 3;
  const int n = (wv >> 2) * 64 + lane;
  if (n >= N) return;

  const int uv = q >> 1;
  const int h = (q & 1) * 32;
  const float* W = ew1 + uv * 64 * 64;

  float acc[32];
  if (uv) {
    #pragma unroll
    for (int j = 0; j < 32; ++j) acc[j] = 0.f;
  } else {
    #pragma unroll
    for (int j = 0; j < 32; ++j) acc[j] = eb1[h + j];
  }
  SEG32(x + (size_t)n * 64, 16, 0, W, h, acc)

  float* dst = (uv ? V : U) + (size_t)n * 64 + h;
  float4* d4 = (float4*)dst;
  #pragma unroll
  for (int c4 = 0; c4 < 8; ++c4)
    d4[c4] = make_float4(acc[c4*4+0], acc[c4*4+1], acc[c4*4+2], acc[c4*4+3]);
}

// ---------------- edge phase: wave/node, LDS-broadcast ea ----------------

__global__ __launch_bounds__(TPB, 4)     // 128-VGPR budget: keep w[32] resident
void k_edge7(const float* __restrict__ U, const float* __restrict__ V,
             const float* __restrict__ ea,
             const float* __restrict__ ew1,
             const int* __restrict__ deg, const int* __restrict__ cur,
             const int2* __restrict__ ec,
             float* __restrict__ H, int N)
{
  __shared__ float sbuf[4 * 256];

  const int lane = threadIdx.x & 63;
  const int wid  = __builtin_amdgcn_readfirstlane(threadIdx.x >> 6);
  const int n    = __builtin_amdgcn_readfirstlane((int)blockIdx.x * 4 + wid);
  if (n >= N) return;

  const int d  = __builtin_amdgcn_readfirstlane(deg[n]);
  const int s0 = __builtin_amdgcn_readfirstlane(cur[n]) - d;

  float* lw = sbuf + wid * 256;
  const int g = lane >> 3;
  const int o = lane & 7;

  // this lane's W1c column — should now stay in VGPRs across the whole loop
  float w[32];
  #pragma unroll
  for (int k = 0; k < 32; ++k) w[k] = ew1[(128 + k) * 64 + lane];

  const float u = U[(size_t)n * 64 + lane];
  const int2* ecp = ec + s0;
  float acc = 0.f;

  for (int i = 0; i < d; i += 8) {
    const int rem = d - i;
    const int gg = (g < rem) ? g : rem - 1;

    const int2 ecv = ecp[i + gg];
    const float4 eav = *(const float4*)(ea + (size_t)ecv.x * 32 + o * 4);

    const int c0 = __builtin_amdgcn_readlane(ecv.y, 0);
    const int c1 = __builtin_amdgcn_readlane(ecv.y, 8);
    const int c2 = __builtin_amdgcn_readlane(ecv.y, 16);
    const int c3 = __builtin_amdgcn_readlane(ecv.y, 24);
    const int c4 = __builtin_amdgcn_readlane(ecv.y, 32);
    const int c5 = __builtin_amdgcn_readlane(ecv.y, 40);
    const int c6 = __builtin_amdgcn_readlane(ecv.y, 48);
    const int c7 = __builtin_amdgcn_readlane(ecv.y, 56);
    const float v0 = V[(size_t)c0 * 64 + lane];
    const float v1 = V[(size_t)c1 * 64 + lane];
    const float v2 = V[(size_t)c2 * 64 + lane];
    const float v3 = V[(size_t)c3 * 64 + lane];
    const float v4 = V[(size_t)c4 * 64 + lane];
    const float v5 = V[(size_t)c5 * 64 + lane];
    const float v6 = V[(size_t)c6 * 64 + lane];
    const float v7 = V[(size_t)c7 * 64 + lane];

    *(float4*)(lw + lane * 4) = eav;     // wave-private strip; DS in-order per wave
    LDS_FENCE();

    const float vs[8] = {v0, v1, v2, v3, v4, v5, v6, v7};
    #pragma unroll
    for (int j = 0; j < 8; ++j) {
      const float* er = lw + j * 32;     // uniform addr -> broadcast reads
      float t0 = u, t1 = 0.f, t2 = 0.f, t3 = 0.f;
      #pragma unroll
      for (int k = 0; k < 32; k += 4) {
        t0 = fmaf(er[k + 0], w[k + 0], t0);
        t1 = fmaf(er[k + 1], w[k + 1], t1);
        t2 = fmaf(er[k + 2], w[k + 2], t2);
        t3 = fmaf(er[k + 3], w[k + 3], t3);
      }
      const float s = fmaxf(((t0 + t1) + (t2 + t3)) + vs[j], 0.f);
      acc += (j < rem) ? s : 0.f;
    }
    LDS_FENCE();                         // strip reads done before next overwrite
  }

  H[(size_t)n * 64 + lane] = acc;
}

// ---------------- node MLP: two half-waves per node group (round 8) ----------------

__global__ __launch_bounds__(TPB)
void k_node3(const float* __restrict__ x, const float* __restrict__ Hin,
             const int* __restrict__ deg,
             const float* __restrict__ ew2, const float* __restrict__ eb2,
             const float* __restrict__ nw1, const float* __restrict__ nb1,
             const float* __restrict__ nw2, const float* __restrict__ nb2,
             float* __restrict__ out, int N)
{
  __shared__ float sb[2][64 * 65];

  const int tid  = threadIdx.x;
  const int wv   = __builtin_amdgcn_readfirstlane(tid >> 6);
  const int lane = tid & 63;
  const int grp  = wv >> 1;
  const int h    = (wv & 1) * 32;

  const int n  = blockIdx.x * 128 + grp * 64 + lane;
  const bool valid = (n < N);
  const int nn = valid ? n : (N - 1);

  float* srow = &sb[grp][lane * 65];

  // stage A: agg = deg*eb2 + H @ ew2
  float acc[32];
  const float dg = (float)deg[nn];
  #pragma unroll
  for (int j = 0; j < 32; ++j) acc[j] = dg * eb2[h + j];
  SEG32(Hin + (size_t)nn * 64, 16, 0, ew2, h, acc)

  #pragma unroll
  for (int j = 0; j < 32; ++j) srow[h + j] = acc[j];
  __syncthreads();

  // stage B: nacc = nb1 + x@nw1[0:64] + agg@nw1[64:128]
  float bcc[32];
  #pragma unroll
  for (int j = 0; j < 32; ++j) bcc[j] = nb1[h + j];
  SEG32(x + (size_t)nn * 64, 16, 0, nw1, h, bcc)
  for (int k = 0; k < 64; ++k) {
    const float ak = srow[k];
    const float* wr = nw1 + (64 + k) * 64 + h;
    #pragma unroll
    for (int cc = 0; cc < 32; ++cc) bcc[cc] = fmaf(ak, wr[cc], bcc[cc]);
  }
  __syncthreads();

  #pragma unroll
  for (int j = 0; j < 32; ++j) srow[h + j] = fmaxf(bcc[j], 0.f);
  __syncthreads();

  // stage C: out = nb2 + relu(nacc) @ nw2
  float occ[32];
  #pragma unroll
  for (int j = 0; j < 32; ++j) occ[j] = nb2[h + j];
  for (int k = 0; k < 64; ++k) {
    const float ak = srow[k];
    const float* wr = nw2 + k * 64 + h;
    #pragma unroll
    for (int cc = 0; cc < 32; ++cc) occ[cc] = fmaf(ak, wr[cc], occ[cc]);
  }

  if (valid) {
    float4* ov = (float4*)(out + (size_t)n * 64 + h);
    #pragma unroll
    for (int c4 = 0; c4 < 8; ++c4)
      ov[c4] = make_float4(occ[c4*4+0], occ[c4*4+1], occ[c4*4+2], occ[c4*4+3]);
  }
}

// ---------------- launch ----------------

extern "C" void kernel_launch(void* const* d_in, const int* in_sizes, int n_in,
                              void* d_out, int out_size, void* d_ws, size_t ws_size,
                              hipStream_t stream) {
  const float* x   = (const float*)d_in[0];
  const int*   ei  = (const int*)d_in[1];
  const float* ea  = (const float*)d_in[2];
  const float* ew1 = (const float*)d_in[3];
  const float* eb1 = (const float*)d_in[4];
  const float* ew2 = (const float*)d_in[5];
  const float* eb2 = (const float*)d_in[6];
  const float* nw1 = (const float*)d_in[7];
  const float* nb1 = (const float*)d_in[8];
  const float* nw2 = (const float*)d_in[9];
  const float* nb2 = (const float*)d_in[10];
  float* out = (float*)d_out;

  const int N = in_sizes[0] / 64;   // 100000
  const int E = in_sizes[1] / 2;    // 1600000

  // workspace layout
  float* U   = (float*)d_ws;                      // N*64 f32
  float* V   = U + (size_t)N * 64;                // N*64 f32
  int* ib    = (int*)(V + (size_t)N * 64);
  int* deg   = ib;                                // N
  int* cur   = ib + N;                            // N
  int* bsum  = ib + 2 * N;                        // <=512
  int2* ec   = (int2*)(ib + 2 * N + 1024);        // E int2
  float* H   = out;

  const int NT = (N + 3) / 4;
  const int NB = (NT + TPB - 1) / TPB;            // 98

  hipMemsetAsync(deg, 0, (size_t)N * sizeof(int), stream);

  k_hist<<<(E + TPB - 1) / TPB, TPB, 0, stream>>>(ei, deg, E);
  k_red<<<NB, TPB, 0, stream>>>(deg, bsum, N);
  k_apply2<<<NB, TPB, 0, stream>>>(deg, bsum, cur, N);
  k_scatter<<<(E + TPB - 1) / TPB, TPB, 0, stream>>>(ei, cur, ec, E);

  {
    const int nwaves = 4 * ((N + 63) / 64);
    const int nblocks = (nwaves + 3) / 4;
    k_prep3<<<nblocks, TPB, 0, stream>>>(x, ew1, eb1, U, V, N);
  }

  k_edge7<<<(N + 3) / 4, TPB, 0, stream>>>(
      U, V, ea, ew1, deg, cur, ec, H, N);

  k_node3<<<(N + 127) / 128, TPB, 0, stream>>>(
      x, H, deg, ew2, eb2, nw1, nb1, nw2, nb2, out, N);
}